// Round 1
// baseline (216.755 us; speedup 1.0000x reference)
//
#include <hip/hip_runtime.h>
#include <math.h>

// Problem constants
#define NB   4
#define CH   256
#define HH   64
#define WWD  64
#define HW   4096          // 64*64
#define GG   8
#define PP   9
#define HP   66
#define WP   66
#define NCOL 216           // 144 offset + 72 mask
#define NPAD 256
#define MTOT 16384         // NB*HW
#define CHW  1048576       // CH*HW
#define EPSV 1e-5f

// ws layout in floats
#define PADSZ   (NB*HP*WP*CH)          // 4,460,544 padded NHWC input
#define OFF_X1  PADSZ                   // x1 (NCHW), later reused as out_nhwc
#define X1SZ    (NB*CH*HW)             // 4,194,304
#define OFF_OM  (OFF_X1 + X1SZ)        // offmask M x 216
#define OMSZ    (MTOT*NCOL)
#define OFF_WC  (OFF_OM + OMSZ)        // combined weights 256 x 256
#define WCSZ    (CH*NPAD)
#define OFF_BI  (OFF_WC + WCSZ)        // bias 256
#define OFF_PT  (OFF_BI + NPAD)        // partials 16384*2
#define OFF_ST  (OFF_PT + MTOT*2)      // stats 8

__device__ __forceinline__ float4 f4fma(float s, float4 v, float4 a) {
    a.x = fmaf(s, v.x, a.x); a.y = fmaf(s, v.y, a.y);
    a.z = fmaf(s, v.z, a.z); a.w = fmaf(s, v.w, a.w);
    return a;
}

// ---------------- prep combined weight + bias ----------------
__global__ __launch_bounds__(256) void prep_w_kernel(
    const float* __restrict__ off_w, const float* __restrict__ off_b,
    const float* __restrict__ mask_w, const float* __restrict__ mask_b,
    float* __restrict__ Wc, float* __restrict__ bias) {
    int idx = blockIdx.x * 256 + threadIdx.x;     // 0..65535
    int k = idx >> 8, j = idx & 255;
    float v = 0.f;
    if (j < 144)      v = off_w[k * 144 + j];
    else if (j < 216) v = mask_w[k * 72 + (j - 144)];
    Wc[k * 256 + j] = v;
    if (k == 0) {
        float b = 0.f;
        if (j < 144)      b = off_b[j];
        else if (j < 216) b = mask_b[j - 144];
        bias[j] = b;
    }
}

// ---------------- NCHW -> padded NHWC transpose ----------------
// grid: 4 * 128 * 8 = 4096 blocks; block 256 (32x8)
__global__ __launch_bounds__(256) void pad_transpose_kernel(
    const float* __restrict__ x, float* __restrict__ inp_pad) {
    __shared__ float tile[32][33];
    int b = blockIdx.x;
    int ct  = b & 7;            // c tile
    int hwt = (b >> 3) & 127;   // hw tile
    int n   = b >> 10;
    int c0 = ct * 32, hw0 = hwt * 32;
    int tx = threadIdx.x & 31, ty = threadIdx.x >> 5;  // ty 0..7
#pragma unroll
    for (int r = 0; r < 4; ++r) {
        int cl = ty + r * 8;
        tile[cl][tx] = x[(size_t)(n * CH + c0 + cl) * HW + hw0 + tx];
    }
    __syncthreads();
#pragma unroll
    for (int r = 0; r < 4; ++r) {
        int hwl = ty + r * 8;
        int hw = hw0 + hwl;
        int h = hw >> 6, w = hw & 63;
        inp_pad[(((size_t)(n * HP + h + 1)) * WP + (w + 1)) * CH + c0 + tx] = tile[tx][hwl];
    }
}

// ---------------- depthwise 3x3 conv + partial stats ----------------
// grid: NB*CH*16 = 16384 blocks; block 256 (256 pixels = 4 rows of 64)
__global__ __launch_bounds__(256) void conv_dw_kernel(
    const float* __restrict__ x, const float* __restrict__ dw_w,
    const float* __restrict__ dw_b, float* __restrict__ x1,
    float* __restrict__ partials) {
    __shared__ float rs1[256], rs2[256];
    int bid = blockIdx.x;
    int chunk = bid & 15;
    int nc = bid >> 4;
    int c = nc & 255;
    int tid = threadIdx.x;
    int pix = chunk * 256 + tid;       // 0..4095
    int h = pix >> 6, w = pix & 63;
    const float* xp = x + (size_t)nc * HW;
    float wgt[9];
#pragma unroll
    for (int i = 0; i < 9; ++i) wgt[i] = dw_w[c * 9 + i];
    float acc = dw_b[c];
#pragma unroll
    for (int dy = -1; dy <= 1; ++dy) {
#pragma unroll
        for (int dx = -1; dx <= 1; ++dx) {
            int hh = h + dy, ww = w + dx;
            if (hh >= 0 && hh < HH && ww >= 0 && ww < WWD)
                acc = fmaf(xp[hh * WWD + ww], wgt[(dy + 1) * 3 + (dx + 1)], acc);
        }
    }
    x1[(size_t)nc * HW + pix] = acc;
    rs1[tid] = acc; rs2[tid] = acc * acc;
    __syncthreads();
    for (int s = 128; s > 0; s >>= 1) {
        if (tid < s) { rs1[tid] += rs1[tid + s]; rs2[tid] += rs2[tid + s]; }
        __syncthreads();
    }
    if (tid == 0) {
        partials[2 * bid]     = rs1[0];
        partials[2 * bid + 1] = rs2[0];
    }
}

// ---------------- finalize stats ----------------
__global__ __launch_bounds__(256) void stats_kernel(
    const float* __restrict__ partials, float* __restrict__ stats) {
    __shared__ float rs1[256], rs2[256];
    int n = blockIdx.x, tid = threadIdx.x;
    float s = 0.f, s2 = 0.f;
    for (int i = tid; i < 4096; i += 256) {
        s  += partials[2 * (n * 4096 + i)];
        s2 += partials[2 * (n * 4096 + i) + 1];
    }
    rs1[tid] = s; rs2[tid] = s2;
    __syncthreads();
    for (int st = 128; st > 0; st >>= 1) {
        if (tid < st) { rs1[tid] += rs1[tid + st]; rs2[tid] += rs2[tid + st]; }
        __syncthreads();
    }
    if (tid == 0) {
        float mean = rs1[0] / (float)CHW;
        float var  = rs2[0] / (float)CHW - mean * mean;
        stats[2 * n]     = mean;
        stats[2 * n + 1] = rsqrtf(var + EPSV);
    }
}

// ---------------- fused norm+gelu GEMM: offmask = gelu(norm(x1)) @ Wc + bias ----------------
// grid: (16384/64)*(256/64) = 1024 blocks; block 256
__global__ __launch_bounds__(256) void gemm_kernel(
    const float* __restrict__ x1, const float* __restrict__ Wc,
    const float* __restrict__ bias, const float* __restrict__ stats,
    const float* __restrict__ gn_g, const float* __restrict__ gn_b,
    float* __restrict__ offmask) {
    __shared__ __align__(16) float As[16][64];
    __shared__ __align__(16) float Bs[16][64];
    int bm = blockIdx.x >> 2, bn = blockIdx.x & 3;
    int m0 = bm * 64, n0 = bn * 64;
    int ns = m0 >> 12;
    int hwbase = m0 & 4095;
    float mean = stats[2 * ns], rsig = stats[2 * ns + 1];
    int tid = threadIdx.x;
    int tx = tid & 15, ty = tid >> 4;
    float acc[4][4] = {};
    for (int k0 = 0; k0 < 256; k0 += 16) {
#pragma unroll
        for (int p = 0; p < 4; ++p) {
            int q = tid + p * 256;
            int kk = q >> 6, mm = q & 63;
            int ch = k0 + kk;
            float v = x1[((size_t)ns * CH + ch) * HW + hwbase + mm];
            v = (v - mean) * rsig * gn_g[ch] + gn_b[ch];
            v = 0.5f * v * (1.0f + erff(v * 0.70710678118654752f));
            As[kk][mm] = v;
            Bs[kk][mm] = Wc[(k0 + kk) * 256 + n0 + mm];
        }
        __syncthreads();
#pragma unroll
        for (int kk = 0; kk < 16; ++kk) {
            float4 a = *(const float4*)&As[kk][ty * 4];
            float4 b = *(const float4*)&Bs[kk][tx * 4];
            float av[4] = {a.x, a.y, a.z, a.w};
            float bv[4] = {b.x, b.y, b.z, b.w};
#pragma unroll
            for (int i = 0; i < 4; ++i)
#pragma unroll
                for (int j = 0; j < 4; ++j)
                    acc[i][j] = fmaf(av[i], bv[j], acc[i][j]);
        }
        __syncthreads();
    }
#pragma unroll
    for (int i = 0; i < 4; ++i) {
        int row = m0 + ty * 4 + i;
#pragma unroll
        for (int j = 0; j < 4; ++j) {
            int col = n0 + tx * 4 + j;
            if (col < NCOL)
                offmask[(size_t)row * NCOL + col] = acc[i][j] + bias[col];
        }
    }
}

// ---------------- DCNv3 core: one wave per pixel ----------------
// grid 4096 blocks; block 256 = 4 waves
__global__ __launch_bounds__(256) void dcn_kernel(
    const float* __restrict__ inp_pad, const float* __restrict__ offmask,
    float* __restrict__ out_nhwc) {
    __shared__ float lom[4][216];
    int wid = threadIdx.x >> 6, lane = threadIdx.x & 63;
    int pixel = blockIdx.x * 4 + wid;
    const float* om = offmask + (size_t)pixel * NCOL;
    for (int i = lane; i < NCOL; i += 64) lom[wid][i] = om[i];
    __syncthreads();
    int g = lane >> 3, c8 = lane & 7;
    int n = pixel >> 12, hw = pixel & 4095;
    int h = hw >> 6, w = hw & 63;
    // softmax over P for this group
    float lg[9];
    float mx = -1e30f;
#pragma unroll
    for (int p = 0; p < 9; ++p) { lg[p] = lom[wid][144 + g * 9 + p]; mx = fmaxf(mx, lg[p]); }
    float sum = 0.f;
#pragma unroll
    for (int p = 0; p < 9; ++p) { lg[p] = expf(lg[p] - mx); sum += lg[p]; }
    float rs = 1.0f / sum;
    const float4* base4 = (const float4*)inp_pad + (size_t)n * HP * WP * (CH / 4);
    int cidx = g * 8 + c8;     // float4 channel index == lane
    float4 acc = make_float4(0.f, 0.f, 0.f, 0.f);
#pragma unroll
    for (int p = 0; p < 9; ++p) {
        float ox = lom[wid][g * 18 + p * 2];
        float oy = lom[wid][g * 18 + p * 2 + 1];
        float px = (float)(w + (p / 3)) + ox;   // = w+1 + (kx-1) + ox in padded coords
        float py = (float)(h + (p % 3)) + oy;
        float xf = floorf(px), yf = floorf(py);
        float wx = px - xf, wy = py - yf;
        int x0 = (int)xf, y0 = (int)yf;
        float m = lg[p] * rs;
        float w00 = m * (1.f - wy) * (1.f - wx);
        float w01 = m * (1.f - wy) * wx;
        float w10 = m * wy * (1.f - wx);
        float w11 = m * wy * wx;
#pragma unroll
        for (int corner = 0; corner < 4; ++corner) {
            int yi = y0 + (corner >> 1);
            int xi = x0 + (corner & 1);
            float cw = (corner == 0) ? w00 : (corner == 1) ? w01 : (corner == 2) ? w10 : w11;
            bool valid = (yi >= 0) & (yi < HP) & (xi >= 0) & (xi < WP);
            int yc = min(max(yi, 0), HP - 1);
            int xc = min(max(xi, 0), WP - 1);
            float4 v = base4[((size_t)yc * WP + xc) * (CH / 4) + cidx];
            float f = valid ? cw : 0.f;
            acc = f4fma(f, v, acc);
        }
    }
    ((float4*)out_nhwc)[(size_t)pixel * 64 + lane] = acc;
}

// ---------------- NHWC -> NCHW output transpose ----------------
__global__ __launch_bounds__(256) void out_transpose_kernel(
    const float* __restrict__ out_nhwc, float* __restrict__ out) {
    __shared__ float tile[32][33];
    int b = blockIdx.x;
    int ct  = b & 7;
    int hwt = (b >> 3) & 127;
    int n   = b >> 10;
    int c0 = ct * 32, hw0 = hwt * 32;
    int tx = threadIdx.x & 31, ty = threadIdx.x >> 5;
#pragma unroll
    for (int r = 0; r < 4; ++r) {
        int hwl = ty + r * 8;
        tile[hwl][tx] = out_nhwc[((size_t)(n * HW + hw0 + hwl)) * CH + c0 + tx];
    }
    __syncthreads();
#pragma unroll
    for (int r = 0; r < 4; ++r) {
        int cl = ty + r * 8;
        out[((size_t)(n * CH + c0 + cl)) * HW + hw0 + tx] = tile[tx][cl];
    }
}

extern "C" void kernel_launch(void* const* d_in, const int* in_sizes, int n_in,
                              void* d_out, int out_size, void* d_ws, size_t ws_size,
                              hipStream_t stream) {
    const float* x      = (const float*)d_in[0];
    const float* dw_w   = (const float*)d_in[1];
    const float* dw_b   = (const float*)d_in[2];
    const float* gn_g   = (const float*)d_in[3];
    const float* gn_b   = (const float*)d_in[4];
    const float* off_w  = (const float*)d_in[5];
    const float* off_b  = (const float*)d_in[6];
    const float* mask_w = (const float*)d_in[7];
    const float* mask_b = (const float*)d_in[8];
    float* out = (float*)d_out;

    float* ws      = (float*)d_ws;
    float* inp_pad = ws;                 // PADSZ
    float* x1      = ws + OFF_X1;        // X1SZ (reused as out_nhwc)
    float* offmask = ws + OFF_OM;        // OMSZ
    float* Wc      = ws + OFF_WC;        // WCSZ
    float* bias    = ws + OFF_BI;        // NPAD
    float* partials= ws + OFF_PT;        // MTOT*2
    float* stats   = ws + OFF_ST;        // 8
    float* out_nhwc = x1;                // alias: x1 dead after gemm

    hipMemsetAsync(inp_pad, 0, (size_t)PADSZ * sizeof(float), stream);
    prep_w_kernel<<<256, 256, 0, stream>>>(off_w, off_b, mask_w, mask_b, Wc, bias);
    pad_transpose_kernel<<<4096, 256, 0, stream>>>(x, inp_pad);
    conv_dw_kernel<<<16384, 256, 0, stream>>>(x, dw_w, dw_b, x1, partials);
    stats_kernel<<<4, 256, 0, stream>>>(partials, stats);
    gemm_kernel<<<1024, 256, 0, stream>>>(x1, Wc, bias, stats, gn_g, gn_b, offmask);
    dcn_kernel<<<4096, 256, 0, stream>>>(inp_pad, offmask, out_nhwc);
    out_transpose_kernel<<<4096, 256, 0, stream>>>(out_nhwc, out);
}

// Round 2
// 177.965 us; speedup vs baseline: 1.2180x; 1.2180x over previous
//
#include <hip/hip_runtime.h>
#include <math.h>

// Problem constants
#define NB   4
#define CH   256
#define HH   64
#define WWD  64
#define HW   4096          // 64*64
#define GG   8
#define PP   9
#define HP   66
#define WP   66
#define NCOL 216           // 144 offset + 72 mask
#define NPAD 256
#define MTOT 16384         // NB*HW
#define CHW  1048576       // CH*HW
#define EPSV 1e-5f

// ws layout in floats
#define PADSZ   (NB*HP*WP*CH)          // 4,460,544 padded NHWC input
#define OFF_X1  PADSZ                   // x1 (NCHW), later reused as out_nhwc
#define X1SZ    (NB*CH*HW)             // 4,194,304
#define OFF_OM  (OFF_X1 + X1SZ)        // offmask M x 216
#define OMSZ    (MTOT*NCOL)
#define OFF_AB  (OFF_OM + OMSZ)        // A bf16 [M][256] -> 2,097,152 floats
#define ABSZ    (MTOT*CH/2)
#define OFF_WB  (OFF_AB + ABSZ)        // Wc_bt bf16 [256][256] -> 32768 floats
#define WBSZ    (CH*NPAD/2)
#define OFF_BI  (OFF_WB + WBSZ)        // bias 256
#define OFF_PT  (OFF_BI + NPAD)        // partials 16384*2
#define OFF_ST  (OFF_PT + MTOT*2)      // stats 8

typedef short bf16x8 __attribute__((ext_vector_type(8)));
typedef float f32x4  __attribute__((ext_vector_type(4)));

__device__ __forceinline__ unsigned short f2bf(float f) {
    unsigned int u = __builtin_bit_cast(unsigned int, f);
    u += 0x7fffu + ((u >> 16) & 1u);           // round-to-nearest-even
    return (unsigned short)(u >> 16);
}

__device__ __forceinline__ float4 f4fma(float s, float4 v, float4 a) {
    a.x = fmaf(s, v.x, a.x); a.y = fmaf(s, v.y, a.y);
    a.z = fmaf(s, v.z, a.z); a.w = fmaf(s, v.w, a.w);
    return a;
}

// ---------------- prep: Wc_bt bf16 [n][k] + bias ----------------
__global__ __launch_bounds__(256) void prep_w_kernel(
    const float* __restrict__ off_w, const float* __restrict__ off_b,
    const float* __restrict__ mask_w, const float* __restrict__ mask_b,
    unsigned short* __restrict__ Wc_bt, float* __restrict__ bias) {
    int idx = blockIdx.x * 256 + threadIdx.x;     // 0..65535
    int k = idx >> 8, n = idx & 255;
    float v = 0.f;
    if (n < 144)      v = off_w[k * 144 + n];
    else if (n < 216) v = mask_w[k * 72 + (n - 144)];
    Wc_bt[(size_t)n * 256 + k] = f2bf(v);
    if (k == 0) {
        float b = 0.f;
        if (n < 144)      b = off_b[n];
        else if (n < 216) b = mask_b[n - 144];
        bias[n] = b;
    }
}

// ---------------- NCHW -> padded NHWC transpose ----------------
__global__ __launch_bounds__(256) void pad_transpose_kernel(
    const float* __restrict__ x, float* __restrict__ inp_pad) {
    __shared__ float tile[32][33];
    int b = blockIdx.x;
    int ct  = b & 7;            // c tile
    int hwt = (b >> 3) & 127;   // hw tile
    int n   = b >> 10;
    int c0 = ct * 32, hw0 = hwt * 32;
    int tx = threadIdx.x & 31, ty = threadIdx.x >> 5;  // ty 0..7
#pragma unroll
    for (int r = 0; r < 4; ++r) {
        int cl = ty + r * 8;
        tile[cl][tx] = x[(size_t)(n * CH + c0 + cl) * HW + hw0 + tx];
    }
    __syncthreads();
#pragma unroll
    for (int r = 0; r < 4; ++r) {
        int hwl = ty + r * 8;
        int hw = hw0 + hwl;
        int h = hw >> 6, w = hw & 63;
        inp_pad[(((size_t)(n * HP + h + 1)) * WP + (w + 1)) * CH + c0 + tx] = tile[tx][hwl];
    }
}

// ---------------- depthwise 3x3 conv + partial stats ----------------
__global__ __launch_bounds__(256) void conv_dw_kernel(
    const float* __restrict__ x, const float* __restrict__ dw_w,
    const float* __restrict__ dw_b, float* __restrict__ x1,
    float* __restrict__ partials) {
    __shared__ float rs1[256], rs2[256];
    int bid = blockIdx.x;
    int chunk = bid & 15;
    int nc = bid >> 4;
    int c = nc & 255;
    int tid = threadIdx.x;
    int pix = chunk * 256 + tid;       // 0..4095
    int h = pix >> 6, w = pix & 63;
    const float* xp = x + (size_t)nc * HW;
    float wgt[9];
#pragma unroll
    for (int i = 0; i < 9; ++i) wgt[i] = dw_w[c * 9 + i];
    float acc = dw_b[c];
#pragma unroll
    for (int dy = -1; dy <= 1; ++dy) {
#pragma unroll
        for (int dx = -1; dx <= 1; ++dx) {
            int hh = h + dy, ww = w + dx;
            if (hh >= 0 && hh < HH && ww >= 0 && ww < WWD)
                acc = fmaf(xp[hh * WWD + ww], wgt[(dy + 1) * 3 + (dx + 1)], acc);
        }
    }
    x1[(size_t)nc * HW + pix] = acc;
    rs1[tid] = acc; rs2[tid] = acc * acc;
    __syncthreads();
    for (int s = 128; s > 0; s >>= 1) {
        if (tid < s) { rs1[tid] += rs1[tid + s]; rs2[tid] += rs2[tid + s]; }
        __syncthreads();
    }
    if (tid == 0) {
        partials[2 * bid]     = rs1[0];
        partials[2 * bid + 1] = rs2[0];
    }
}

// ---------------- finalize stats ----------------
__global__ __launch_bounds__(256) void stats_kernel(
    const float* __restrict__ partials, float* __restrict__ stats) {
    __shared__ float rs1[256], rs2[256];
    int n = blockIdx.x, tid = threadIdx.x;
    float s = 0.f, s2 = 0.f;
    for (int i = tid; i < 4096; i += 256) {
        s  += partials[2 * (n * 4096 + i)];
        s2 += partials[2 * (n * 4096 + i) + 1];
    }
    rs1[tid] = s; rs2[tid] = s2;
    __syncthreads();
    for (int st = 128; st > 0; st >>= 1) {
        if (tid < st) { rs1[tid] += rs1[tid + st]; rs2[tid] += rs2[tid + st]; }
        __syncthreads();
    }
    if (tid == 0) {
        float mean = rs1[0] / (float)CHW;
        float var  = rs2[0] / (float)CHW - mean * mean;
        stats[2 * n]     = mean;
        stats[2 * n + 1] = rsqrtf(var + EPSV);
    }
}

// ---------------- norm+gelu once, transpose to A bf16 [m][k] ----------------
// grid 4096 blocks (4 n * 8 ctile * 128 hwtile), block 256
__global__ __launch_bounds__(256) void gelu_pass_kernel(
    const float* __restrict__ x1, const float* __restrict__ stats,
    const float* __restrict__ gn_g, const float* __restrict__ gn_b,
    unsigned short* __restrict__ A) {
    __shared__ float tile[32][33];
    int b = blockIdx.x;
    int ct  = b & 7;
    int hwt = (b >> 3) & 127;
    int n   = b >> 10;
    int c0 = ct * 32, hw0 = hwt * 32;
    float mean = stats[2 * n], rsig = stats[2 * n + 1];
    int tx = threadIdx.x & 31, ty = threadIdx.x >> 5;
#pragma unroll
    for (int r = 0; r < 4; ++r) {
        int cl = ty + r * 8;
        int ch = c0 + cl;
        float v = x1[((size_t)(n * CH + ch)) * HW + hw0 + tx];
        v = (v - mean) * rsig * gn_g[ch] + gn_b[ch];
        v = 0.5f * v * (1.0f + erff(v * 0.70710678118654752f));
        tile[cl][tx] = v;
    }
    __syncthreads();
    int r2 = threadIdx.x >> 3;       // local hw 0..31
    int cg = threadIdx.x & 7;        // 4-channel group
    int m = n * HW + hw0 + r2;
    ushort4 o;
    o.x = f2bf(tile[cg * 4 + 0][r2]);
    o.y = f2bf(tile[cg * 4 + 1][r2]);
    o.z = f2bf(tile[cg * 4 + 2][r2]);
    o.w = f2bf(tile[cg * 4 + 3][r2]);
    *(ushort4*)&A[(size_t)m * 256 + c0 + cg * 4] = o;
}

// ---------------- bf16 MFMA GEMM: offmask = A @ W + bias ----------------
// A [M][256] bf16 row-major, Wc_bt [n][k] bf16. Tile 128x128xK64, 4 waves 2x2.
#define LDK 72
__global__ __launch_bounds__(256) void gemm_mfma_kernel(
    const unsigned short* __restrict__ A, const unsigned short* __restrict__ Bt,
    const float* __restrict__ bias, float* __restrict__ offmask) {
    __shared__ unsigned short As[128 * LDK];
    __shared__ unsigned short Bs[128 * LDK];
    int m0 = (blockIdx.x >> 1) * 128;
    int n0 = (blockIdx.x & 1) * 128;
    int tid = threadIdx.x;
    int lane = tid & 63, wid = tid >> 6;
    int wm = (wid >> 1) * 64, wn = (wid & 1) * 64;
    f32x4 acc[4][4] = {};
    for (int k0 = 0; k0 < 256; k0 += 64) {
#pragma unroll
        for (int i = 0; i < 4; ++i) {
            int q = tid + i * 256;
            int mm = q >> 3, kk = (q & 7) * 8;
            *(uint4*)&As[mm * LDK + kk] = *(const uint4*)&A[(size_t)(m0 + mm) * 256 + k0 + kk];
            *(uint4*)&Bs[mm * LDK + kk] = *(const uint4*)&Bt[(size_t)(n0 + mm) * 256 + k0 + kk];
        }
        __syncthreads();
#pragma unroll
        for (int kh = 0; kh < 2; ++kh) {
            bf16x8 af[4], bfr[4];
#pragma unroll
            for (int i = 0; i < 4; ++i) {
                af[i]  = *(const bf16x8*)&As[(wm + i * 16 + (lane & 15)) * LDK + kh * 32 + (lane >> 4) * 8];
                bfr[i] = *(const bf16x8*)&Bs[(wn + i * 16 + (lane & 15)) * LDK + kh * 32 + (lane >> 4) * 8];
            }
#pragma unroll
            for (int mi = 0; mi < 4; ++mi)
#pragma unroll
                for (int nj = 0; nj < 4; ++nj)
                    acc[mi][nj] = __builtin_amdgcn_mfma_f32_16x16x32_bf16(
                        af[mi], bfr[nj], acc[mi][nj], 0, 0, 0);
        }
        __syncthreads();
    }
    int colbase = n0 + wn + (lane & 15);
    int rowq = lane >> 4;
#pragma unroll
    for (int mi = 0; mi < 4; ++mi)
#pragma unroll
        for (int nj = 0; nj < 4; ++nj) {
            int col = colbase + nj * 16;
            if (col < NCOL) {
                float bcol = bias[col];
#pragma unroll
                for (int r = 0; r < 4; ++r) {
                    int row = m0 + wm + mi * 16 + rowq * 4 + r;
                    offmask[(size_t)row * NCOL + col] = acc[mi][nj][r] + bcol;
                }
            }
        }
}

// ---------------- DCNv3 core: one wave per pixel ----------------
__global__ __launch_bounds__(256) void dcn_kernel(
    const float* __restrict__ inp_pad, const float* __restrict__ offmask,
    float* __restrict__ out_nhwc) {
    __shared__ float lom[4][216];
    int wid = threadIdx.x >> 6, lane = threadIdx.x & 63;
    int pixel = blockIdx.x * 4 + wid;
    const float* om = offmask + (size_t)pixel * NCOL;
    for (int i = lane; i < NCOL; i += 64) lom[wid][i] = om[i];
    __syncthreads();
    int g = lane >> 3, c8 = lane & 7;
    int n = pixel >> 12, hw = pixel & 4095;
    int h = hw >> 6, w = hw & 63;
    float lg[9];
    float mx = -1e30f;
#pragma unroll
    for (int p = 0; p < 9; ++p) { lg[p] = lom[wid][144 + g * 9 + p]; mx = fmaxf(mx, lg[p]); }
    float sum = 0.f;
#pragma unroll
    for (int p = 0; p < 9; ++p) { lg[p] = expf(lg[p] - mx); sum += lg[p]; }
    float rs = 1.0f / sum;
    const float4* base4 = (const float4*)inp_pad + (size_t)n * HP * WP * (CH / 4);
    int cidx = g * 8 + c8;
    float4 acc = make_float4(0.f, 0.f, 0.f, 0.f);
#pragma unroll
    for (int p = 0; p < 9; ++p) {
        float ox = lom[wid][g * 18 + p * 2];
        float oy = lom[wid][g * 18 + p * 2 + 1];
        float px = (float)(w + (p / 3)) + ox;
        float py = (float)(h + (p % 3)) + oy;
        float xf = floorf(px), yf = floorf(py);
        float wx = px - xf, wy = py - yf;
        int x0 = (int)xf, y0 = (int)yf;
        float m = lg[p] * rs;
        float w00 = m * (1.f - wy) * (1.f - wx);
        float w01 = m * (1.f - wy) * wx;
        float w10 = m * wy * (1.f - wx);
        float w11 = m * wy * wx;
#pragma unroll
        for (int corner = 0; corner < 4; ++corner) {
            int yi = y0 + (corner >> 1);
            int xi = x0 + (corner & 1);
            float cw = (corner == 0) ? w00 : (corner == 1) ? w01 : (corner == 2) ? w10 : w11;
            bool valid = (yi >= 0) & (yi < HP) & (xi >= 0) & (xi < WP);
            int yc = min(max(yi, 0), HP - 1);
            int xc = min(max(xi, 0), WP - 1);
            float4 v = base4[((size_t)yc * WP + xc) * (CH / 4) + cidx];
            float f = valid ? cw : 0.f;
            acc = f4fma(f, v, acc);
        }
    }
    ((float4*)out_nhwc)[(size_t)pixel * 64 + lane] = acc;
}

// ---------------- NHWC -> NCHW output transpose ----------------
__global__ __launch_bounds__(256) void out_transpose_kernel(
    const float* __restrict__ out_nhwc, float* __restrict__ out) {
    __shared__ float tile[32][33];
    int b = blockIdx.x;
    int ct  = b & 7;
    int hwt = (b >> 3) & 127;
    int n   = b >> 10;
    int c0 = ct * 32, hw0 = hwt * 32;
    int tx = threadIdx.x & 31, ty = threadIdx.x >> 5;
#pragma unroll
    for (int r = 0; r < 4; ++r) {
        int hwl = ty + r * 8;
        tile[hwl][tx] = out_nhwc[((size_t)(n * HW + hw0 + hwl)) * CH + c0 + tx];
    }
    __syncthreads();
#pragma unroll
    for (int r = 0; r < 4; ++r) {
        int cl = ty + r * 8;
        out[((size_t)(n * CH + c0 + cl)) * HW + hw0 + tx] = tile[tx][cl];
    }
}

extern "C" void kernel_launch(void* const* d_in, const int* in_sizes, int n_in,
                              void* d_out, int out_size, void* d_ws, size_t ws_size,
                              hipStream_t stream) {
    const float* x      = (const float*)d_in[0];
    const float* dw_w   = (const float*)d_in[1];
    const float* dw_b   = (const float*)d_in[2];
    const float* gn_g   = (const float*)d_in[3];
    const float* gn_b   = (const float*)d_in[4];
    const float* off_w  = (const float*)d_in[5];
    const float* off_b  = (const float*)d_in[6];
    const float* mask_w = (const float*)d_in[7];
    const float* mask_b = (const float*)d_in[8];
    float* out = (float*)d_out;

    float* ws      = (float*)d_ws;
    float* inp_pad = ws;                 // PADSZ
    float* x1      = ws + OFF_X1;        // X1SZ (reused as out_nhwc)
    float* offmask = ws + OFF_OM;        // OMSZ
    unsigned short* Abf   = (unsigned short*)(ws + OFF_AB);
    unsigned short* Wc_bt = (unsigned short*)(ws + OFF_WB);
    float* bias    = ws + OFF_BI;
    float* partials= ws + OFF_PT;
    float* stats   = ws + OFF_ST;
    float* out_nhwc = x1;                // alias: x1 dead after gelu_pass+gemm

    hipMemsetAsync(inp_pad, 0, (size_t)PADSZ * sizeof(float), stream);
    prep_w_kernel<<<256, 256, 0, stream>>>(off_w, off_b, mask_w, mask_b, Wc_bt, bias);
    pad_transpose_kernel<<<4096, 256, 0, stream>>>(x, inp_pad);
    conv_dw_kernel<<<16384, 256, 0, stream>>>(x, dw_w, dw_b, x1, partials);
    stats_kernel<<<4, 256, 0, stream>>>(partials, stats);
    gelu_pass_kernel<<<4096, 256, 0, stream>>>(x1, stats, gn_g, gn_b, Abf);
    gemm_mfma_kernel<<<256, 256, 0, stream>>>(Abf, Wc_bt, bias, offmask);
    dcn_kernel<<<4096, 256, 0, stream>>>(inp_pad, offmask, out_nhwc);
    out_transpose_kernel<<<4096, 256, 0, stream>>>(out_nhwc, out);
}

// Round 3
// 166.979 us; speedup vs baseline: 1.2981x; 1.0658x over previous
//
#include <hip/hip_runtime.h>
#include <math.h>

// Problem constants
#define NB   4
#define CH   256
#define HH   64
#define WWD  64
#define HW   4096          // 64*64
#define GG   8
#define PP   9
#define NCOL 216           // 144 offset + 72 mask
#define NPAD 256
#define MTOT 16384         // NB*HW
#define CHW  1048576       // CH*HW
#define EPSV 1e-5f

// ws layout in floats
#define NHWCSZ  (NB*HW*CH)             // 4,194,304 unpadded NHWC input
#define OFF_X1  NHWCSZ                  // x1 (NCHW), later reused as out_nhwc
#define X1SZ    (NB*CH*HW)             // 4,194,304
#define OFF_OM  (OFF_X1 + X1SZ)        // offmask M x 216
#define OMSZ    (MTOT*NCOL)
#define OFF_AB  (OFF_OM + OMSZ)        // A bf16 [M][256] -> 2,097,152 floats
#define ABSZ    (MTOT*CH/2)
#define OFF_WB  (OFF_AB + ABSZ)        // Wc_bt bf16 [256][256] -> 32768 floats
#define WBSZ    (CH*NPAD/2)
#define OFF_BI  (OFF_WB + WBSZ)        // bias 256
#define OFF_PT  (OFF_BI + NPAD)        // partials 16384*2
#define OFF_ST  (OFF_PT + MTOT*2)      // stats 8

typedef short bf16x8 __attribute__((ext_vector_type(8)));
typedef float f32x4  __attribute__((ext_vector_type(4)));

__device__ __forceinline__ unsigned short f2bf(float f) {
    unsigned int u = __builtin_bit_cast(unsigned int, f);
    u += 0x7fffu + ((u >> 16) & 1u);           // round-to-nearest-even
    return (unsigned short)(u >> 16);
}

__device__ __forceinline__ float4 f4fma(float s, float4 v, float4 a) {
    a.x = fmaf(s, v.x, a.x); a.y = fmaf(s, v.y, a.y);
    a.z = fmaf(s, v.z, a.z); a.w = fmaf(s, v.w, a.w);
    return a;
}

// ---------------- prep: Wc_bt bf16 [n][k] + bias ----------------
__global__ __launch_bounds__(256) void prep_w_kernel(
    const float* __restrict__ off_w, const float* __restrict__ off_b,
    const float* __restrict__ mask_w, const float* __restrict__ mask_b,
    unsigned short* __restrict__ Wc_bt, float* __restrict__ bias) {
    int idx = blockIdx.x * 256 + threadIdx.x;     // 0..65535
    int k = idx >> 8, n = idx & 255;
    float v = 0.f;
    if (n < 144)      v = off_w[k * 144 + n];
    else if (n < 216) v = mask_w[k * 72 + (n - 144)];
    Wc_bt[(size_t)n * 256 + k] = f2bf(v);
    if (k == 0) {
        float b = 0.f;
        if (n < 144)      b = off_b[n];
        else if (n < 216) b = mask_b[n - 144];
        bias[n] = b;
    }
}

// ---------------- NCHW -> NHWC transpose (unpadded) ----------------
// grid: 4 * 128 * 8 = 4096 blocks; block 256 (32x8)
__global__ __launch_bounds__(256) void transpose_nhwc_kernel(
    const float* __restrict__ x, float* __restrict__ inp_nhwc) {
    __shared__ float tile[32][33];
    int b = blockIdx.x;
    int ct  = b & 7;            // c tile
    int hwt = (b >> 3) & 127;   // hw tile
    int n   = b >> 10;
    int c0 = ct * 32, hw0 = hwt * 32;
    int tx = threadIdx.x & 31, ty = threadIdx.x >> 5;  // ty 0..7
#pragma unroll
    for (int r = 0; r < 4; ++r) {
        int cl = ty + r * 8;
        tile[cl][tx] = x[(size_t)(n * CH + c0 + cl) * HW + hw0 + tx];
    }
    __syncthreads();
#pragma unroll
    for (int r = 0; r < 4; ++r) {
        int hwl = ty + r * 8;
        inp_nhwc[((size_t)(n * HW + hw0 + hwl)) * CH + c0 + tx] = tile[tx][hwl];
    }
}

// ---------------- depthwise 3x3 conv + partial stats ----------------
__global__ __launch_bounds__(256) void conv_dw_kernel(
    const float* __restrict__ x, const float* __restrict__ dw_w,
    const float* __restrict__ dw_b, float* __restrict__ x1,
    float* __restrict__ partials) {
    __shared__ float rs1[256], rs2[256];
    int bid = blockIdx.x;
    int chunk = bid & 15;
    int nc = bid >> 4;
    int c = nc & 255;
    int tid = threadIdx.x;
    int pix = chunk * 256 + tid;       // 0..4095
    int h = pix >> 6, w = pix & 63;
    const float* xp = x + (size_t)nc * HW;
    float wgt[9];
#pragma unroll
    for (int i = 0; i < 9; ++i) wgt[i] = dw_w[c * 9 + i];
    float acc = dw_b[c];
#pragma unroll
    for (int dy = -1; dy <= 1; ++dy) {
#pragma unroll
        for (int dx = -1; dx <= 1; ++dx) {
            int hh = h + dy, ww = w + dx;
            if (hh >= 0 && hh < HH && ww >= 0 && ww < WWD)
                acc = fmaf(xp[hh * WWD + ww], wgt[(dy + 1) * 3 + (dx + 1)], acc);
        }
    }
    x1[(size_t)nc * HW + pix] = acc;
    rs1[tid] = acc; rs2[tid] = acc * acc;
    __syncthreads();
    for (int s = 128; s > 0; s >>= 1) {
        if (tid < s) { rs1[tid] += rs1[tid + s]; rs2[tid] += rs2[tid + s]; }
        __syncthreads();
    }
    if (tid == 0) {
        partials[2 * bid]     = rs1[0];
        partials[2 * bid + 1] = rs2[0];
    }
}

// ---------------- finalize stats ----------------
__global__ __launch_bounds__(256) void stats_kernel(
    const float* __restrict__ partials, float* __restrict__ stats) {
    __shared__ float rs1[256], rs2[256];
    int n = blockIdx.x, tid = threadIdx.x;
    float s = 0.f, s2 = 0.f;
    for (int i = tid; i < 4096; i += 256) {
        s  += partials[2 * (n * 4096 + i)];
        s2 += partials[2 * (n * 4096 + i) + 1];
    }
    rs1[tid] = s; rs2[tid] = s2;
    __syncthreads();
    for (int st = 128; st > 0; st >>= 1) {
        if (tid < st) { rs1[tid] += rs1[tid + st]; rs2[tid] += rs2[tid + st]; }
        __syncthreads();
    }
    if (tid == 0) {
        float mean = rs1[0] / (float)CHW;
        float var  = rs2[0] / (float)CHW - mean * mean;
        stats[2 * n]     = mean;
        stats[2 * n + 1] = rsqrtf(var + EPSV);
    }
}

// ---------------- norm+gelu once, transpose to A bf16 [m][k] ----------------
// grid 4096 blocks (4 n * 8 ctile * 128 hwtile), block 256
__global__ __launch_bounds__(256) void gelu_pass_kernel(
    const float* __restrict__ x1, const float* __restrict__ stats,
    const float* __restrict__ gn_g, const float* __restrict__ gn_b,
    unsigned short* __restrict__ A) {
    __shared__ float tile[32][33];
    int b = blockIdx.x;
    int ct  = b & 7;
    int hwt = (b >> 3) & 127;
    int n   = b >> 10;
    int c0 = ct * 32, hw0 = hwt * 32;
    float mean = stats[2 * n], rsig = stats[2 * n + 1];
    int tx = threadIdx.x & 31, ty = threadIdx.x >> 5;
#pragma unroll
    for (int r = 0; r < 4; ++r) {
        int cl = ty + r * 8;
        int ch = c0 + cl;
        float v = x1[((size_t)(n * CH + ch)) * HW + hw0 + tx];
        v = (v - mean) * rsig * gn_g[ch] + gn_b[ch];
        v = 0.5f * v * (1.0f + erff(v * 0.70710678118654752f));
        tile[cl][tx] = v;
    }
    __syncthreads();
    int r2 = threadIdx.x >> 3;       // local hw 0..31
    int cg = threadIdx.x & 7;        // 4-channel group
    int m = n * HW + hw0 + r2;
    ushort4 o;
    o.x = f2bf(tile[cg * 4 + 0][r2]);
    o.y = f2bf(tile[cg * 4 + 1][r2]);
    o.z = f2bf(tile[cg * 4 + 2][r2]);
    o.w = f2bf(tile[cg * 4 + 3][r2]);
    *(ushort4*)&A[(size_t)m * 256 + c0 + cg * 4] = o;
}

// ---------------- bf16 MFMA GEMM: offmask = A @ W + bias ----------------
// A [M][256] bf16 row-major, Wc_bt [n][k] bf16.
// Tile 64x64, 4 waves each 32x32 (2x2 MFMA). grid 1024 blocks -> 4+/CU.
#define LDK 72
__global__ __launch_bounds__(256) void gemm_mfma_kernel(
    const unsigned short* __restrict__ A, const unsigned short* __restrict__ Bt,
    const float* __restrict__ bias, float* __restrict__ offmask) {
    __shared__ unsigned short As[64 * LDK];
    __shared__ unsigned short Bs[64 * LDK];
    int m0 = (blockIdx.x >> 2) * 64;
    int n0 = (blockIdx.x & 3) * 64;
    int tid = threadIdx.x;
    int lane = tid & 63, wid = tid >> 6;
    int wm = (wid >> 1) * 32, wn = (wid & 1) * 32;
    f32x4 acc[2][2] = {};
    for (int k0 = 0; k0 < 256; k0 += 64) {
#pragma unroll
        for (int i = 0; i < 2; ++i) {
            int q = tid + i * 256;
            int mm = q >> 3, kk = (q & 7) * 8;
            *(uint4*)&As[mm * LDK + kk] = *(const uint4*)&A[(size_t)(m0 + mm) * 256 + k0 + kk];
            *(uint4*)&Bs[mm * LDK + kk] = *(const uint4*)&Bt[(size_t)(n0 + mm) * 256 + k0 + kk];
        }
        __syncthreads();
#pragma unroll
        for (int kh = 0; kh < 2; ++kh) {
            bf16x8 af[2], bfr[2];
#pragma unroll
            for (int i = 0; i < 2; ++i) {
                af[i]  = *(const bf16x8*)&As[(wm + i * 16 + (lane & 15)) * LDK + kh * 32 + (lane >> 4) * 8];
                bfr[i] = *(const bf16x8*)&Bs[(wn + i * 16 + (lane & 15)) * LDK + kh * 32 + (lane >> 4) * 8];
            }
#pragma unroll
            for (int mi = 0; mi < 2; ++mi)
#pragma unroll
                for (int nj = 0; nj < 2; ++nj)
                    acc[mi][nj] = __builtin_amdgcn_mfma_f32_16x16x32_bf16(
                        af[mi], bfr[nj], acc[mi][nj], 0, 0, 0);
        }
        __syncthreads();
    }
    int colbase = n0 + wn + (lane & 15);
    int rowq = lane >> 4;
#pragma unroll
    for (int mi = 0; mi < 2; ++mi)
#pragma unroll
        for (int nj = 0; nj < 2; ++nj) {
            int col = colbase + nj * 16;
            if (col < NCOL) {
                float bcol = bias[col];
#pragma unroll
                for (int r = 0; r < 4; ++r) {
                    int row = m0 + wm + mi * 16 + rowq * 4 + r;
                    offmask[(size_t)row * NCOL + col] = acc[mi][nj][r] + bcol;
                }
            }
        }
}

// ---------------- DCNv3 core: one wave per pixel (unpadded NHWC input) ----------------
__global__ __launch_bounds__(256) void dcn_kernel(
    const float* __restrict__ inp_nhwc, const float* __restrict__ offmask,
    float* __restrict__ out_nhwc) {
    __shared__ float lom[4][216];
    int wid = threadIdx.x >> 6, lane = threadIdx.x & 63;
    int pixel = blockIdx.x * 4 + wid;
    const float* om = offmask + (size_t)pixel * NCOL;
    for (int i = lane; i < NCOL; i += 64) lom[wid][i] = om[i];
    __syncthreads();
    int g = lane >> 3, c8 = lane & 7;
    int n = pixel >> 12, hw = pixel & 4095;
    int h = hw >> 6, w = hw & 63;
    float lg[9];
    float mx = -1e30f;
#pragma unroll
    for (int p = 0; p < 9; ++p) { lg[p] = lom[wid][144 + g * 9 + p]; mx = fmaxf(mx, lg[p]); }
    float sum = 0.f;
#pragma unroll
    for (int p = 0; p < 9; ++p) { lg[p] = expf(lg[p] - mx); sum += lg[p]; }
    float rs = 1.0f / sum;
    const float4* base4 = (const float4*)inp_nhwc + (size_t)n * HW * (CH / 4);
    int cidx = g * 8 + c8;     // float4 channel index == lane
    float4 acc = make_float4(0.f, 0.f, 0.f, 0.f);
#pragma unroll
    for (int p = 0; p < 9; ++p) {
        float ox = lom[wid][g * 18 + p * 2];
        float oy = lom[wid][g * 18 + p * 2 + 1];
        // padded coords: sample at (py,px); pad ring is zeros -> valid iff 1<=yi<=64
        float px = (float)(w + (p / 3)) + ox;
        float py = (float)(h + (p % 3)) + oy;
        float xf = floorf(px), yf = floorf(py);
        float wx = px - xf, wy = py - yf;
        int x0 = (int)xf, y0 = (int)yf;
        float m = lg[p] * rs;
        float w00 = m * (1.f - wy) * (1.f - wx);
        float w01 = m * (1.f - wy) * wx;
        float w10 = m * wy * (1.f - wx);
        float w11 = m * wy * wx;
#pragma unroll
        for (int corner = 0; corner < 4; ++corner) {
            int yi = y0 + (corner >> 1);
            int xi = x0 + (corner & 1);
            float cw = (corner == 0) ? w00 : (corner == 1) ? w01 : (corner == 2) ? w10 : w11;
            bool valid = (yi >= 1) & (yi <= 64) & (xi >= 1) & (xi <= 64);
            int yc = min(max(yi, 1), 64) - 1;
            int xc = min(max(xi, 1), 64) - 1;
            float4 v = base4[((size_t)yc * WWD + xc) * (CH / 4) + cidx];
            float f = valid ? cw : 0.f;
            acc = f4fma(f, v, acc);
        }
    }
    ((float4*)out_nhwc)[(size_t)pixel * 64 + lane] = acc;
}

// ---------------- NHWC -> NCHW output transpose ----------------
__global__ __launch_bounds__(256) void out_transpose_kernel(
    const float* __restrict__ out_nhwc, float* __restrict__ out) {
    __shared__ float tile[32][33];
    int b = blockIdx.x;
    int ct  = b & 7;
    int hwt = (b >> 3) & 127;
    int n   = b >> 10;
    int c0 = ct * 32, hw0 = hwt * 32;
    int tx = threadIdx.x & 31, ty = threadIdx.x >> 5;
#pragma unroll
    for (int r = 0; r < 4; ++r) {
        int hwl = ty + r * 8;
        tile[hwl][tx] = out_nhwc[((size_t)(n * HW + hw0 + hwl)) * CH + c0 + tx];
    }
    __syncthreads();
#pragma unroll
    for (int r = 0; r < 4; ++r) {
        int cl = ty + r * 8;
        out[((size_t)(n * CH + c0 + cl)) * HW + hw0 + tx] = tile[tx][cl];
    }
}

extern "C" void kernel_launch(void* const* d_in, const int* in_sizes, int n_in,
                              void* d_out, int out_size, void* d_ws, size_t ws_size,
                              hipStream_t stream) {
    const float* x      = (const float*)d_in[0];
    const float* dw_w   = (const float*)d_in[1];
    const float* dw_b   = (const float*)d_in[2];
    const float* gn_g   = (const float*)d_in[3];
    const float* gn_b   = (const float*)d_in[4];
    const float* off_w  = (const float*)d_in[5];
    const float* off_b  = (const float*)d_in[6];
    const float* mask_w = (const float*)d_in[7];
    const float* mask_b = (const float*)d_in[8];
    float* out = (float*)d_out;

    float* ws       = (float*)d_ws;
    float* inp_nhwc = ws;                 // NHWCSZ
    float* x1       = ws + OFF_X1;        // X1SZ (reused as out_nhwc)
    float* offmask  = ws + OFF_OM;        // OMSZ
    unsigned short* Abf   = (unsigned short*)(ws + OFF_AB);
    unsigned short* Wc_bt = (unsigned short*)(ws + OFF_WB);
    float* bias    = ws + OFF_BI;
    float* partials= ws + OFF_PT;
    float* stats   = ws + OFF_ST;
    float* out_nhwc = x1;                 // alias: x1 dead after gelu_pass

    prep_w_kernel<<<256, 256, 0, stream>>>(off_w, off_b, mask_w, mask_b, Wc_bt, bias);
    transpose_nhwc_kernel<<<4096, 256, 0, stream>>>(x, inp_nhwc);
    conv_dw_kernel<<<16384, 256, 0, stream>>>(x, dw_w, dw_b, x1, partials);
    stats_kernel<<<4, 256, 0, stream>>>(partials, stats);
    gelu_pass_kernel<<<4096, 256, 0, stream>>>(x1, stats, gn_g, gn_b, Abf);
    gemm_mfma_kernel<<<1024, 256, 0, stream>>>(Abf, Wc_bt, bias, offmask);
    dcn_kernel<<<4096, 256, 0, stream>>>(inp_nhwc, offmask, out_nhwc);
    out_transpose_kernel<<<4096, 256, 0, stream>>>(out_nhwc, out);
}